// Round 1
// baseline (3103.221 us; speedup 1.0000x reference)
//
#include <hip/hip_runtime.h>
#include <math.h>

#define N_NODES 8192
#define N_EDGES 262144

__device__ __forceinline__ float sspf(float x){
    // softplus(x) - ln(2), numerically stable
    float sp = (x > 20.0f) ? x : log1pf(expf(x));
    return sp - 0.6931471805599453f;
}

// ---------------------------------------------------------------------------
// Kernel A: per-node q = lin_irreps(s, Wq0, Wq1); out = sc (self-connection)
// block = 128 threads (one per output channel), grid = N
// q layout per node (128 floats): [q0[0..31], q1[u][c] at 32+u*3+c]
// out layout matches reference concat([sc0, sc1.reshape(N,96)],1)
// ---------------------------------------------------------------------------
__global__ __launch_bounds__(128) void node_kernel(
    const float* __restrict__ feats, const float* __restrict__ attrs,
    const float* __restrict__ Wq0, const float* __restrict__ Wq1,
    const float* __restrict__ Ws0, const float* __restrict__ Ws1,
    float* __restrict__ qbuf, float* __restrict__ out)
{
    int n = blockIdx.x; int t = threadIdx.x;
    __shared__ float sf[128];
    __shared__ float sa[16];
    sf[t] = feats[n*128 + t];
    if (t < 16) sa[t] = attrs[n*16 + t];
    __syncthreads();
    const float inv_sqrt32 = 0.17677669529663687f;   // 1/sqrt(32)
    const float sc_scale   = 0.04419417382415922f;   // 1/sqrt(32*16)
    float qv, scv;
    if (t < 32){
        int v = t;
        float acc = 0.f;
        for (int u = 0; u < 32; ++u) acc += sf[u] * Wq0[u*32 + v];
        qv = acc * inv_sqrt32;
        acc = 0.f;
        for (int u = 0; u < 32; ++u){
            float su = sf[u];
            for (int a = 0; a < 16; ++a)
                acc += su * sa[a] * Ws0[(u*16 + a)*32 + v];
        }
        scv = acc * sc_scale;
    } else {
        int k = t - 32; int v = k/3; int c = k - v*3;
        float acc = 0.f;
        for (int u = 0; u < 32; ++u) acc += sf[32 + u*3 + c] * Wq1[u*32 + v];
        qv = acc * inv_sqrt32;
        acc = 0.f;
        for (int u = 0; u < 32; ++u){
            float su = sf[32 + u*3 + c];
            for (int a = 0; a < 16; ++a)
                acc += su * sa[a] * Ws1[(u*16 + a)*32 + v];
        }
        scv = acc * sc_scale;
    }
    qbuf[n*128 + t] = qv;
    out[n*128 + t]  = scv;
}

// ---------------------------------------------------------------------------
// Edge pass 1: k-path -> d -> expv; atomicAdd z[dst].
// One wave64 per edge; 4 waves (4 edges) per 256-thread block.
// ---------------------------------------------------------------------------
__global__ __launch_bounds__(256) void edge_pass1(
    const float* __restrict__ feats, const float* __restrict__ emb,
    const float* __restrict__ eattr, const int* __restrict__ eidx,
    const float* __restrict__ Wk1, const float* __restrict__ Wk2,
    const float* __restrict__ Wlk0, const float* __restrict__ Wlk1,
    const float* __restrict__ Wd0, const float* __restrict__ Wd1,
    const float* __restrict__ qbuf,
    float* __restrict__ expv_buf, float* __restrict__ zbuf)
{
    int wave = threadIdx.x >> 6, lane = threadIdx.x & 63;
    int e = blockIdx.x*4 + wave;
    __shared__ float s_xs[4][128];
    __shared__ float s_q [4][128];
    __shared__ float s_em[4][16];
    __shared__ float s_y [4][4];
    __shared__ float s_h [4][64];
    __shared__ float s_w [4][128];
    __shared__ float s_km0[4][64];
    __shared__ float s_km1[4][192];
    __shared__ float s_k [4][128];

    int src = eidx[e], dst = eidx[N_EDGES + e];
    s_xs[wave][lane]    = feats[src*128 + lane];
    s_xs[wave][64+lane] = feats[src*128 + 64 + lane];
    s_q [wave][lane]    = qbuf[dst*128 + lane];
    s_q [wave][64+lane] = qbuf[dst*128 + 64 + lane];
    if (lane < 16) s_em[wave][lane] = emb[e*16 + lane];
    if (lane < 4)  s_y [wave][lane] = eattr[e*4 + lane];
    __syncthreads();

    // h = ssp(emb @ Wk1 / 4), 64 outputs, one per lane
    {
        float acc = 0.f;
        for (int a = 0; a < 16; ++a) acc += s_em[wave][a] * Wk1[a*64 + lane];
        s_h[wave][lane] = sspf(acc * 0.25f);
    }
    __syncthreads();

    // wk = h @ Wk2 / 8, 128 outputs, two per lane
    for (int r = 0; r < 2; ++r){
        int wi = lane + 64*r;
        float acc = 0.f;
        for (int u = 0; u < 64; ++u) acc += s_h[wave][u] * Wk2[u*128 + wi];
        s_w[wave][wi] = acc * 0.125f;
    }
    __syncthreads();

    // uvu tensor product -> km (64 scalar + 64x3 vector channels)
    {
        float y0  = s_y[wave][0];
        float y1a = s_y[wave][1], y1b = s_y[wave][2], y1c = s_y[wave][3];
        if (lane < 32){
            int u = lane;
            float x0 = s_xs[wave][u];
            s_km0[wave][u] = s_w[wave][u] * x0 * y0;              // o0a
            float w1 = s_w[wave][32+u];
            s_km1[wave][u*3+0] = w1 * x0 * y1a;                   // o1a
            s_km1[wave][u*3+1] = w1 * x0 * y1b;
            s_km1[wave][u*3+2] = w1 * x0 * y1c;
        } else {
            int u = lane - 32;
            float xa = s_xs[wave][32+u*3+0];
            float xb = s_xs[wave][32+u*3+1];
            float xc = s_xs[wave][32+u*3+2];
            float dotv = xa*y1a + xb*y1b + xc*y1c;
            s_km0[wave][32+u] = s_w[wave][96+u] * dotv * 0.5773502691896258f; // o0b
            float w2 = s_w[wave][64+u];
            s_km1[wave][(32+u)*3+0] = w2 * xa * y0;               // o1b
            s_km1[wave][(32+u)*3+1] = w2 * xb * y0;
            s_km1[wave][(32+u)*3+2] = w2 * xc * y0;
        }
    }
    __syncthreads();

    // k = lin(km): k0 (32) + k1 (32x3), 128 outputs, two per lane
    for (int r = 0; r < 2; ++r){
        int o = lane + 64*r;
        int v = o & 31, p = o >> 5;
        float acc = 0.f;
        if (p == 0){
            for (int u = 0; u < 64; ++u) acc += s_km0[wave][u] * Wlk0[u*32+v];
            s_k[wave][v] = acc * 0.125f;
        } else {
            int c = p - 1;
            for (int u = 0; u < 64; ++u) acc += s_km1[wave][u*3+c] * Wlk1[u*32+v];
            s_k[wave][32 + v*3 + c] = acc * 0.125f;
        }
    }
    __syncthreads();

    // d = (q0 . (Wd0 k0) + sum_c q1[:,c] . (Wd1 k1[:,c]) / sqrt3) / sqrt(2048)
    float part;
    if (lane < 32){
        int u = lane;
        float tacc = 0.f;
        for (int v = 0; v < 32; ++v) tacc += Wd0[u*32+v] * s_k[wave][v];
        part = s_q[wave][u] * tacc;
    } else {
        int u = lane - 32;
        part = 0.f;
        for (int c = 0; c < 3; ++c){
            float tacc = 0.f;
            for (int v = 0; v < 32; ++v) tacc += Wd1[u*32+v] * s_k[wave][32+v*3+c];
            part += s_q[wave][32+u*3+c] * tacc;
        }
        part *= 0.5773502691896258f;
    }
    for (int off = 32; off > 0; off >>= 1) part += __shfl_xor(part, off);
    if (lane == 0){
        float d = part * 0.022097086912079608f;  // 1/sqrt(2*32*32)
        // reference bug reproduced: diff = pos[src]-pos[src] == 0
        float el = sqrtf(1e-12f);
        float xcut = 10.0f * (1.0f - el*0.2f);
        float cutoff = (xcut > 0.f) ? expf(-1.0f / fmaxf(xcut, 1e-6f)) : 0.f;
        float ev = cutoff * expf(d);
        expv_buf[e] = ev;
        atomicAdd(&zbuf[dst], ev);
    }
}

// ---------------------------------------------------------------------------
// Edge pass 2: v-path; msg = sqrt(alpha) * v; atomicAdd into out[dst].
// ---------------------------------------------------------------------------
__global__ __launch_bounds__(256) void edge_pass2(
    const float* __restrict__ feats, const float* __restrict__ emb,
    const float* __restrict__ eattr, const int* __restrict__ eidx,
    const float* __restrict__ Wv1, const float* __restrict__ Wv2,
    const float* __restrict__ Wlv0, const float* __restrict__ Wlv1,
    const float* __restrict__ expv_buf, const float* __restrict__ zbuf,
    float* __restrict__ out)
{
    int wave = threadIdx.x >> 6, lane = threadIdx.x & 63;
    int e = blockIdx.x*4 + wave;
    __shared__ float s_xs[4][128];
    __shared__ float s_em[4][16];
    __shared__ float s_y [4][4];
    __shared__ float s_h [4][64];
    __shared__ float s_w [4][128];
    __shared__ float s_km0[4][64];
    __shared__ float s_km1[4][192];
    __shared__ float s_v [4][128];

    int src = eidx[e], dst = eidx[N_EDGES + e];
    s_xs[wave][lane]    = feats[src*128 + lane];
    s_xs[wave][64+lane] = feats[src*128 + 64 + lane];
    if (lane < 16) s_em[wave][lane] = emb[e*16 + lane];
    if (lane < 4)  s_y [wave][lane] = eattr[e*4 + lane];
    __syncthreads();

    {
        float acc = 0.f;
        for (int a = 0; a < 16; ++a) acc += s_em[wave][a] * Wv1[a*64 + lane];
        s_h[wave][lane] = sspf(acc * 0.25f);
    }
    __syncthreads();

    for (int r = 0; r < 2; ++r){
        int wi = lane + 64*r;
        float acc = 0.f;
        for (int u = 0; u < 64; ++u) acc += s_h[wave][u] * Wv2[u*128 + wi];
        s_w[wave][wi] = acc * 0.125f;
    }
    __syncthreads();

    {
        float y0  = s_y[wave][0];
        float y1a = s_y[wave][1], y1b = s_y[wave][2], y1c = s_y[wave][3];
        if (lane < 32){
            int u = lane;
            float x0 = s_xs[wave][u];
            s_km0[wave][u] = s_w[wave][u] * x0 * y0;
            float w1 = s_w[wave][32+u];
            s_km1[wave][u*3+0] = w1 * x0 * y1a;
            s_km1[wave][u*3+1] = w1 * x0 * y1b;
            s_km1[wave][u*3+2] = w1 * x0 * y1c;
        } else {
            int u = lane - 32;
            float xa = s_xs[wave][32+u*3+0];
            float xb = s_xs[wave][32+u*3+1];
            float xc = s_xs[wave][32+u*3+2];
            float dotv = xa*y1a + xb*y1b + xc*y1c;
            s_km0[wave][32+u] = s_w[wave][96+u] * dotv * 0.5773502691896258f;
            float w2 = s_w[wave][64+u];
            s_km1[wave][(32+u)*3+0] = w2 * xa * y0;
            s_km1[wave][(32+u)*3+1] = w2 * xb * y0;
            s_km1[wave][(32+u)*3+2] = w2 * xc * y0;
        }
    }
    __syncthreads();

    for (int r = 0; r < 2; ++r){
        int o = lane + 64*r;
        int v = o & 31, p = o >> 5;
        float acc = 0.f;
        if (p == 0){
            for (int u = 0; u < 64; ++u) acc += s_km0[wave][u] * Wlv0[u*32+v];
            s_v[wave][v] = acc * 0.125f;
        } else {
            int c = p - 1;
            for (int u = 0; u < 64; ++u) acc += s_km1[wave][u*3+c] * Wlv1[u*32+v];
            s_v[wave][32 + v*3 + c] = acc * 0.125f;
        }
    }
    __syncthreads();

    float ev = expv_buf[e];
    float zz = zbuf[dst];
    zz = (zz == 0.f) ? 1.f : zz;
    float alpha = ev / zz;
    float coef = sqrtf(fmaxf(alpha, 0.f));
    for (int r = 0; r < 2; ++r){
        int o = lane + 64*r;
        atomicAdd(&out[dst*128 + o], coef * s_v[wave][o]);
    }
}

extern "C" void kernel_launch(void* const* d_in, const int* in_sizes, int n_in,
                              void* d_out, int out_size, void* d_ws, size_t ws_size,
                              hipStream_t stream)
{
    const float* feats = (const float*)d_in[0];
    const float* attrs = (const float*)d_in[1];
    const float* emb   = (const float*)d_in[2];
    const float* eattr = (const float*)d_in[3];
    // d_in[4] positions: unused (reference computes positions[src]-positions[src] == 0)
    const float* Wq0  = (const float*)d_in[5];
    const float* Wq1  = (const float*)d_in[6];
    const float* Wk1  = (const float*)d_in[7];
    const float* Wk2  = (const float*)d_in[8];
    const float* Wv1  = (const float*)d_in[9];
    const float* Wv2  = (const float*)d_in[10];
    const float* Wlk0 = (const float*)d_in[11];
    const float* Wlk1 = (const float*)d_in[12];
    const float* Wlv0 = (const float*)d_in[13];
    const float* Wlv1 = (const float*)d_in[14];
    const float* Wd0  = (const float*)d_in[15];
    const float* Wd1  = (const float*)d_in[16];
    const float* Ws0  = (const float*)d_in[17];
    const float* Ws1  = (const float*)d_in[18];
    const int*   eidx = (const int*)d_in[19];

    float* out  = (float*)d_out;
    float* qbuf = (float*)d_ws;                 // N*128 floats
    float* expv = qbuf + (size_t)N_NODES*128;   // E floats
    float* zbuf = expv + (size_t)N_EDGES;       // N floats

    hipMemsetAsync(zbuf, 0, N_NODES*sizeof(float), stream);
    node_kernel<<<N_NODES, 128, 0, stream>>>(feats, attrs, Wq0, Wq1, Ws0, Ws1, qbuf, out);
    edge_pass1<<<N_EDGES/4, 256, 0, stream>>>(feats, emb, eattr, eidx,
                                              Wk1, Wk2, Wlk0, Wlk1, Wd0, Wd1,
                                              qbuf, expv, zbuf);
    edge_pass2<<<N_EDGES/4, 256, 0, stream>>>(feats, emb, eattr, eidx,
                                              Wv1, Wv2, Wlv0, Wlv1,
                                              expv, zbuf, out);
}

// Round 2
// 1147.137 us; speedup vs baseline: 2.7052x; 2.7052x over previous
//
#include <hip/hip_runtime.h>
#include <math.h>

#define N_NODES 8192
#define N_EDGES 262144
#define INV_SQRT3 0.5773502691896258f

__device__ __forceinline__ float sspf(float x){
    // softplus(x) - ln(2), numerically stable
    float sp = (x > 20.0f) ? x : log1pf(expf(x));
    return sp - 0.6931471805599453f;
}

// ---------------------------------------------------------------------------
// Kernel A: per-node q = lin_irreps(s, Wq0, Wq1); out = sc (self-connection)
// (unchanged from R1 — not the bottleneck)
// ---------------------------------------------------------------------------
__global__ __launch_bounds__(128) void node_kernel(
    const float* __restrict__ feats, const float* __restrict__ attrs,
    const float* __restrict__ Wq0, const float* __restrict__ Wq1,
    const float* __restrict__ Ws0, const float* __restrict__ Ws1,
    float* __restrict__ qbuf, float* __restrict__ out)
{
    int n = blockIdx.x; int t = threadIdx.x;
    __shared__ float sf[128];
    __shared__ float sa[16];
    sf[t] = feats[n*128 + t];
    if (t < 16) sa[t] = attrs[n*16 + t];
    __syncthreads();
    const float inv_sqrt32 = 0.17677669529663687f;   // 1/sqrt(32)
    const float sc_scale   = 0.04419417382415922f;   // 1/sqrt(32*16)
    float qv, scv;
    if (t < 32){
        int v = t;
        float acc = 0.f;
        for (int u = 0; u < 32; ++u) acc += sf[u] * Wq0[u*32 + v];
        qv = acc * inv_sqrt32;
        acc = 0.f;
        for (int u = 0; u < 32; ++u){
            float su = sf[u];
            for (int a = 0; a < 16; ++a)
                acc += su * sa[a] * Ws0[(u*16 + a)*32 + v];
        }
        scv = acc * sc_scale;
    } else {
        int k = t - 32; int v = k/3; int c = k - v*3;
        float acc = 0.f;
        for (int u = 0; u < 32; ++u) acc += sf[32 + u*3 + c] * Wq1[u*32 + v];
        qv = acc * inv_sqrt32;
        acc = 0.f;
        for (int u = 0; u < 32; ++u){
            float su = sf[32 + u*3 + c];
            for (int a = 0; a < 16; ++a)
                acc += su * sa[a] * Ws1[(u*16 + a)*32 + v];
        }
        scv = acc * sc_scale;
    }
    qbuf[n*128 + t] = qv;
    out[n*128 + t]  = scv;
}

// ---------------------------------------------------------------------------
// Edge pass 1: weights in LDS, 1 wave = 64 edges (2 at a time).
// LDS (15360 dwords = 61440 B, 2 blocks/CU):
//   Wk2  @ 0      (8192)
//   Wlk0 @ 8192   (2048)
//   Wlk1 @ 10240  (2048)
//   scratch @ 12288: 4 waves x 2 edges x 384 dwords
// per-edge scratch (384): A[0..191] h->km1->q, C[192..255] km0, D[256..383] w->k
// ---------------------------------------------------------------------------
__global__ __launch_bounds__(256, 2) void edge_pass1(
    const float* __restrict__ feats, const float* __restrict__ emb,
    const float* __restrict__ eattr, const int* __restrict__ eidx,
    const float* __restrict__ Wk1, const float* __restrict__ Wk2,
    const float* __restrict__ Wlk0, const float* __restrict__ Wlk1,
    const float* __restrict__ Wd0, const float* __restrict__ Wd1,
    const float* __restrict__ qbuf,
    float* __restrict__ expv_buf, float* __restrict__ zbuf)
{
    __shared__ float lds[15360];
    const int t = threadIdx.x;
    for (int i = t*4; i < 8192; i += 1024) *(float4*)&lds[i]       = *(const float4*)&Wk2 [i];
    for (int i = t*4; i < 2048; i += 1024) *(float4*)&lds[8192+i]  = *(const float4*)&Wlk0[i];
    for (int i = t*4; i < 2048; i += 1024) *(float4*)&lds[10240+i] = *(const float4*)&Wlk1[i];
    __syncthreads();

    const int wv   = __builtin_amdgcn_readfirstlane(t >> 6);
    const int lane = t & 63;
    const int eb0  = 12288 + wv*768;
    const int eb1  = eb0 + 384;

    // lin-stage lane constants: lane owns outputs o=2*lane, 2*lane+1
    const int p    = lane >> 4;                 // 0..3
    const int v0   = (2*lane) & 31;
    const int linw = ((p==0)? 8192 : 10240) + v0;
    const int kmoff= (p==0)? 192 : (p-1);       // km0 @192 stride1 ; km1 @0+c stride3
    const int kstep= (p==0)? 1 : 3;
    const int kw0  = (p==0)? (256+v0)   : (256+32+v0*3+(p-1));
    const int kw1  = (p==0)? (256+v0+1) : (256+32+(v0+1)*3+(p-1));

    // uvu lane constants (w lives in D region @256)
    const bool low = lane < 32;
    const int uvA  = 256 + (low? lane    : 96+(lane-32));
    const int uvB  = 256 + (low? 32+lane : 64+(lane-32));
    const int xsi  = low? lane : (32 + 3*(lane-32));

    // d-stage lane constants (transposed: lane owns column v of Wd)
    const int half = lane >> 5; const int dv = lane & 31;
    const float* __restrict__ wdp0 = (half? Wd1 : Wd0) + dv;
    const int qi1 = half? 1 : 0, qi2 = half? 2 : 0;
    const int qstep = half? 3 : 1;
    const int qrel  = half? 32 : 0;

    const int ebase = (blockIdx.x*4 + wv) * 64;

    for (int it = 0; it < 32; ++it){
        const int e0 = __builtin_amdgcn_readfirstlane(ebase + 2*it);
        const int e1 = e0 + 1;
        const int src0 = eidx[e0], dst0 = eidx[N_EDGES+e0];
        const int src1 = eidx[e1], dst1 = eidx[N_EDGES+e1];

        // ---- GEMM1: h = ssp(emb @ Wk1 / 4), h[lane] per edge -> A ----
        {
            float a0=0.f, a1=0.f;
            const float* em0 = emb + (size_t)e0*16;
            const float* em1 = emb + (size_t)e1*16;
            #pragma unroll
            for (int a = 0; a < 16; ++a){
                float w = Wk1[a*64 + lane];
                a0 += em0[a]*w; a1 += em1[a]*w;
            }
            lds[eb0+lane] = sspf(a0*0.25f);
            lds[eb1+lane] = sspf(a1*0.25f);
        }
        __syncthreads();

        // ---- GEMM2: w = h @ Wk2 / 8 -> D ----
        {
            float f0=0,f1=0,g0=0,g1=0;
            const float4* h0p = (const float4*)&lds[eb0];
            const float4* h1p = (const float4*)&lds[eb1];
            #pragma unroll
            for (int u4 = 0; u4 < 16; ++u4){
                float4 h0 = h0p[u4], h1 = h1p[u4];
                #pragma unroll
                for (int j = 0; j < 4; ++j){
                    float2 w2 = *(const float2*)&lds[(u4*4+j)*128 + 2*lane];
                    float hh0 = (&h0.x)[j], hh1 = (&h1.x)[j];
                    f0 += hh0*w2.x; f1 += hh0*w2.y;
                    g0 += hh1*w2.x; g1 += hh1*w2.y;
                }
            }
            float2 o0; o0.x = f0*0.125f; o0.y = f1*0.125f;
            float2 o1; o1.x = g0*0.125f; o1.y = g1*0.125f;
            *(float2*)&lds[eb0+256 + 2*lane] = o0;
            *(float2*)&lds[eb1+256 + 2*lane] = o1;
        }
        __syncthreads();

        // ---- uvu tensor product -> km0 (C), km1 (A; h dead) ----
        {
            const float y00 = eattr[(size_t)e0*4+0], y0a = eattr[(size_t)e0*4+1],
                        y0b = eattr[(size_t)e0*4+2], y0c = eattr[(size_t)e0*4+3];
            const float y10 = eattr[(size_t)e1*4+0], y1a = eattr[(size_t)e1*4+1],
                        y1b = eattr[(size_t)e1*4+2], y1c = eattr[(size_t)e1*4+3];
            const float* fp0 = feats + (size_t)src0*128 + xsi;
            const float* fp1 = feats + (size_t)src1*128 + xsi;
            float xa0 = fp0[0], xb0 = fp0[1], xc0 = fp0[2];
            float xa1 = fp1[0], xb1 = fp1[1], xc1 = fp1[2];

            float wA0 = lds[eb0+uvA], wB0 = lds[eb0+uvB];
            float wA1 = lds[eb1+uvA], wB1 = lds[eb1+uvB];

            float dot0 = xa0*y0a + xb0*y0b + xc0*y0c;
            float km00 = wA0 * (low ? xa0*y00 : dot0*INV_SQRT3);
            float pm0  = wB0 * (low ? xa0 : y00);
            float t00  = low ? y0a : xa0, t01 = low ? y0b : xb0, t02 = low ? y0c : xc0;
            lds[eb0+192+lane] = km00;
            lds[eb0+3*lane+0] = pm0*t00;
            lds[eb0+3*lane+1] = pm0*t01;
            lds[eb0+3*lane+2] = pm0*t02;

            float dot1 = xa1*y1a + xb1*y1b + xc1*y1c;
            float km01 = wA1 * (low ? xa1*y10 : dot1*INV_SQRT3);
            float pm1  = wB1 * (low ? xa1 : y10);
            float t10  = low ? y1a : xa1, t11 = low ? y1b : xb1, t12 = low ? y1c : xc1;
            lds[eb1+192+lane] = km01;
            lds[eb1+3*lane+0] = pm1*t10;
            lds[eb1+3*lane+1] = pm1*t11;
            lds[eb1+3*lane+2] = pm1*t12;
        }
        __syncthreads();

        // ---- lin: k = lin(km) /8 -> D (w dead) ; then q -> A (km1 dead) ----
        {
            float l00=0,l01=0,l10=0,l11=0;
            int ka = eb0 + kmoff, kb = eb1 + kmoff, wo = linw;
            #pragma unroll 8
            for (int u = 0; u < 64; ++u){
                float2 w2 = *(const float2*)&lds[wo];
                float m0 = lds[ka], m1 = lds[kb];
                wo += 32; ka += kstep; kb += kstep;
                l00 += m0*w2.x; l01 += m0*w2.y;
                l10 += m1*w2.x; l11 += m1*w2.y;
            }
            lds[eb0+kw0] = l00*0.125f; lds[eb0+kw1] = l01*0.125f;
            lds[eb1+kw0] = l10*0.125f; lds[eb1+kw1] = l11*0.125f;

            // q gather (dst uniform -> coalesced); DS in-order: writes follow km reads
            lds[eb0+lane]    = qbuf[(size_t)dst0*128 + lane];
            lds[eb0+64+lane] = qbuf[(size_t)dst0*128 + 64 + lane];
            lds[eb1+lane]    = qbuf[(size_t)dst1*128 + lane];
            lds[eb1+64+lane] = qbuf[(size_t)dst1*128 + 64 + lane];
        }
        __syncthreads();

        // ---- d = (q0.(Wd0 k0) + sum_c q1c.(Wd1 k1c)/sqrt3)/sqrt(2048) ----
        #pragma unroll
        for (int ee = 0; ee < 2; ++ee){
            const int eb = ee? eb1 : eb0;
            const int e  = ee? e1  : e0;
            const int dn = ee? dst1 : dst0;
            float b0=0,b1=0,b2=0;
            int qa = eb + qrel;
            const float* wp = wdp0;
            #pragma unroll 4
            for (int u = 0; u < 32; ++u){
                float w = wp[0]; wp += 32;
                float r0 = lds[qa], r1 = lds[qa+qi1], r2 = lds[qa+qi2];
                qa += qstep;
                b0 += r0*w; b1 += r1*w; b2 += r2*w;
            }
            float part;
            if (half == 0){
                part = b0 * lds[eb+256+dv];
            } else {
                part = (b0*lds[eb+256+32+3*dv+0] + b1*lds[eb+256+32+3*dv+1]
                      + b2*lds[eb+256+32+3*dv+2]) * INV_SQRT3;
            }
            #pragma unroll
            for (int off = 32; off > 0; off >>= 1) part += __shfl_xor(part, off);
            if (lane == 0){
                float d = part * 0.022097086912079608f;     // 1/sqrt(2*32*32)
                // cutoff: diff = pos[src]-pos[src] == 0 (reference bug), constant
                float ev = 0.9048374180359595f * expf(d);
                expv_buf[e] = ev;
                atomicAdd(&zbuf[dn], ev);
            }
        }
    }
}

// ---------------------------------------------------------------------------
// Edge pass 2: v-path; msg = sqrt(alpha) * v; atomicAdd into out[dst].
// Same structure, no d/q stage. LDS: Wv2@0, Wlv0@8192, Wlv1@10240, scratch.
// ---------------------------------------------------------------------------
__global__ __launch_bounds__(256, 2) void edge_pass2(
    const float* __restrict__ feats, const float* __restrict__ emb,
    const float* __restrict__ eattr, const int* __restrict__ eidx,
    const float* __restrict__ Wv1, const float* __restrict__ Wv2,
    const float* __restrict__ Wlv0, const float* __restrict__ Wlv1,
    const float* __restrict__ expv_buf, const float* __restrict__ zbuf,
    float* __restrict__ out)
{
    __shared__ float lds[15360];
    const int t = threadIdx.x;
    for (int i = t*4; i < 8192; i += 1024) *(float4*)&lds[i]       = *(const float4*)&Wv2 [i];
    for (int i = t*4; i < 2048; i += 1024) *(float4*)&lds[8192+i]  = *(const float4*)&Wlv0[i];
    for (int i = t*4; i < 2048; i += 1024) *(float4*)&lds[10240+i] = *(const float4*)&Wlv1[i];
    __syncthreads();

    const int wv   = __builtin_amdgcn_readfirstlane(t >> 6);
    const int lane = t & 63;
    const int eb0  = 12288 + wv*768;
    const int eb1  = eb0 + 384;

    const int p    = lane >> 4;
    const int v0   = (2*lane) & 31;
    const int linw = ((p==0)? 8192 : 10240) + v0;
    const int kmoff= (p==0)? 192 : (p-1);
    const int kstep= (p==0)? 1 : 3;
    const int kw0  = (p==0)? (256+v0)   : (256+32+v0*3+(p-1));
    const int kw1  = (p==0)? (256+v0+1) : (256+32+(v0+1)*3+(p-1));

    const bool low = lane < 32;
    const int uvA  = 256 + (low? lane    : 96+(lane-32));
    const int uvB  = 256 + (low? 32+lane : 64+(lane-32));
    const int xsi  = low? lane : (32 + 3*(lane-32));

    const int ebase = (blockIdx.x*4 + wv) * 64;

    for (int it = 0; it < 32; ++it){
        const int e0 = __builtin_amdgcn_readfirstlane(ebase + 2*it);
        const int e1 = e0 + 1;
        const int src0 = eidx[e0], dst0 = eidx[N_EDGES+e0];
        const int src1 = eidx[e1], dst1 = eidx[N_EDGES+e1];

        {
            float a0=0.f, a1=0.f;
            const float* em0 = emb + (size_t)e0*16;
            const float* em1 = emb + (size_t)e1*16;
            #pragma unroll
            for (int a = 0; a < 16; ++a){
                float w = Wv1[a*64 + lane];
                a0 += em0[a]*w; a1 += em1[a]*w;
            }
            lds[eb0+lane] = sspf(a0*0.25f);
            lds[eb1+lane] = sspf(a1*0.25f);
        }
        __syncthreads();

        {
            float f0=0,f1=0,g0=0,g1=0;
            const float4* h0p = (const float4*)&lds[eb0];
            const float4* h1p = (const float4*)&lds[eb1];
            #pragma unroll
            for (int u4 = 0; u4 < 16; ++u4){
                float4 h0 = h0p[u4], h1 = h1p[u4];
                #pragma unroll
                for (int j = 0; j < 4; ++j){
                    float2 w2 = *(const float2*)&lds[(u4*4+j)*128 + 2*lane];
                    float hh0 = (&h0.x)[j], hh1 = (&h1.x)[j];
                    f0 += hh0*w2.x; f1 += hh0*w2.y;
                    g0 += hh1*w2.x; g1 += hh1*w2.y;
                }
            }
            float2 o0; o0.x = f0*0.125f; o0.y = f1*0.125f;
            float2 o1; o1.x = g0*0.125f; o1.y = g1*0.125f;
            *(float2*)&lds[eb0+256 + 2*lane] = o0;
            *(float2*)&lds[eb1+256 + 2*lane] = o1;
        }
        __syncthreads();

        {
            const float y00 = eattr[(size_t)e0*4+0], y0a = eattr[(size_t)e0*4+1],
                        y0b = eattr[(size_t)e0*4+2], y0c = eattr[(size_t)e0*4+3];
            const float y10 = eattr[(size_t)e1*4+0], y1a = eattr[(size_t)e1*4+1],
                        y1b = eattr[(size_t)e1*4+2], y1c = eattr[(size_t)e1*4+3];
            const float* fp0 = feats + (size_t)src0*128 + xsi;
            const float* fp1 = feats + (size_t)src1*128 + xsi;
            float xa0 = fp0[0], xb0 = fp0[1], xc0 = fp0[2];
            float xa1 = fp1[0], xb1 = fp1[1], xc1 = fp1[2];

            float wA0 = lds[eb0+uvA], wB0 = lds[eb0+uvB];
            float wA1 = lds[eb1+uvA], wB1 = lds[eb1+uvB];

            float dot0 = xa0*y0a + xb0*y0b + xc0*y0c;
            float km00 = wA0 * (low ? xa0*y00 : dot0*INV_SQRT3);
            float pm0  = wB0 * (low ? xa0 : y00);
            float t00  = low ? y0a : xa0, t01 = low ? y0b : xb0, t02 = low ? y0c : xc0;
            lds[eb0+192+lane] = km00;
            lds[eb0+3*lane+0] = pm0*t00;
            lds[eb0+3*lane+1] = pm0*t01;
            lds[eb0+3*lane+2] = pm0*t02;

            float dot1 = xa1*y1a + xb1*y1b + xc1*y1c;
            float km01 = wA1 * (low ? xa1*y10 : dot1*INV_SQRT3);
            float pm1  = wB1 * (low ? xa1 : y10);
            float t10  = low ? y1a : xa1, t11 = low ? y1b : xb1, t12 = low ? y1c : xc1;
            lds[eb1+192+lane] = km01;
            lds[eb1+3*lane+0] = pm1*t10;
            lds[eb1+3*lane+1] = pm1*t11;
            lds[eb1+3*lane+2] = pm1*t12;
        }
        __syncthreads();

        {
            float l00=0,l01=0,l10=0,l11=0;
            int ka = eb0 + kmoff, kb = eb1 + kmoff, wo = linw;
            #pragma unroll 8
            for (int u = 0; u < 64; ++u){
                float2 w2 = *(const float2*)&lds[wo];
                float m0 = lds[ka], m1 = lds[kb];
                wo += 32; ka += kstep; kb += kstep;
                l00 += m0*w2.x; l01 += m0*w2.y;
                l10 += m1*w2.x; l11 += m1*w2.y;
            }
            lds[eb0+kw0] = l00*0.125f; lds[eb0+kw1] = l01*0.125f;
            lds[eb1+kw0] = l10*0.125f; lds[eb1+kw1] = l11*0.125f;
        }
        __syncthreads();

        #pragma unroll
        for (int ee = 0; ee < 2; ++ee){
            const int eb = ee? eb1 : eb0;
            const int e  = ee? e1  : e0;
            const int dn = ee? dst1 : dst0;
            float ev = expv_buf[e];
            float zz = zbuf[dn];
            zz = (zz == 0.f) ? 1.f : zz;
            float coef = sqrtf(fmaxf(ev/zz, 0.f));
            float2 vv = *(const float2*)&lds[eb+256 + 2*lane];
            float* op = out + (size_t)dn*128 + 2*lane;
            atomicAdd(op,   coef*vv.x);
            atomicAdd(op+1, coef*vv.y);
        }
    }
}

extern "C" void kernel_launch(void* const* d_in, const int* in_sizes, int n_in,
                              void* d_out, int out_size, void* d_ws, size_t ws_size,
                              hipStream_t stream)
{
    const float* feats = (const float*)d_in[0];
    const float* attrs = (const float*)d_in[1];
    const float* emb   = (const float*)d_in[2];
    const float* eattr = (const float*)d_in[3];
    // d_in[4] positions: unused (reference computes positions[src]-positions[src] == 0)
    const float* Wq0  = (const float*)d_in[5];
    const float* Wq1  = (const float*)d_in[6];
    const float* Wk1  = (const float*)d_in[7];
    const float* Wk2  = (const float*)d_in[8];
    const float* Wv1  = (const float*)d_in[9];
    const float* Wv2  = (const float*)d_in[10];
    const float* Wlk0 = (const float*)d_in[11];
    const float* Wlk1 = (const float*)d_in[12];
    const float* Wlv0 = (const float*)d_in[13];
    const float* Wlv1 = (const float*)d_in[14];
    const float* Wd0  = (const float*)d_in[15];
    const float* Wd1  = (const float*)d_in[16];
    const float* Ws0  = (const float*)d_in[17];
    const float* Ws1  = (const float*)d_in[18];
    const int*   eidx = (const int*)d_in[19];

    float* out  = (float*)d_out;
    float* qbuf = (float*)d_ws;                 // N*128 floats
    float* expv = qbuf + (size_t)N_NODES*128;   // E floats
    float* zbuf = expv + (size_t)N_EDGES;       // N floats

    hipMemsetAsync(zbuf, 0, N_NODES*sizeof(float), stream);
    node_kernel<<<N_NODES, 128, 0, stream>>>(feats, attrs, Wq0, Wq1, Ws0, Ws1, qbuf, out);
    edge_pass1<<<N_EDGES/256, 256, 0, stream>>>(feats, emb, eattr, eidx,
                                                Wk1, Wk2, Wlk0, Wlk1, Wd0, Wd1,
                                                qbuf, expv, zbuf);
    edge_pass2<<<N_EDGES/256, 256, 0, stream>>>(feats, emb, eattr, eidx,
                                                Wv1, Wv2, Wlv0, Wlv1,
                                                expv, zbuf, out);
}